// Round 22
// baseline (62.576 us; speedup 1.0000x reference)
//
#include <hip/hip_runtime.h>
#include <math.h>

typedef _Float16 half8 __attribute__((ext_vector_type(8)));
typedef _Float16 half4 __attribute__((ext_vector_type(4)));
typedef float    f32x4 __attribute__((ext_vector_type(4)));

#define TOKENS  32768
#define HIDDEN  2048
#define EXPERTS 64
#define TOPK    8
#define BKW     64               // k per staged window
#define NWIN    (HIDDEN / BKW)   // 32
#define LDH     72               // LDS row stride in halves (144 B: 16B-aligned)

// ---------------------------------------------------------------------------
// r21 = r15 (best, 61.2us) with exactly two deltas:
//  (1) K-loop barriers are raw `s_waitcnt lgkmcnt(0)` + s_barrier (NO implicit
//      vmcnt(0) drain -- global prefetches stay in flight across barriers;
//      counted vmcnt at the cvt-use point enforces the data dependency).
//  (2) A prefetched TWO windows deep via a second static A register set
//      (+16 VGPR; W stays 1-deep: it is L2-resident, ~250cyc).
// A in-flight time: ~1 full window + stage (~1500cyc >> 900cyc HBM latency).
// Everything else identical to r15: fused kernel, fp16x3 split numerics
// (hi*hi + hi*lo + lo*hi, fp32 acc), 256 thr / 4 waves / 64 tok x 64 exp,
// single-buffered LDS, inline fp32->hi/lo staging, verified frag layouts.
// ---------------------------------------------------------------------------
__global__ __launch_bounds__(256, 1)
void router_p2(const float* __restrict__ A,
               const float* __restrict__ W,
               const float* __restrict__ bias,
               float* __restrict__ out) {
    __shared__ __align__(16) _Float16 hsm[4 * 64 * LDH];   // Ahi|Alo|Whi|Wlo = 36864 B
    _Float16* Ahs = hsm;
    _Float16* Als = hsm + 64 * LDH;
    _Float16* Whs = hsm + 2 * 64 * LDH;
    _Float16* Wls = hsm + 3 * 64 * LDH;

    const int tid = threadIdx.x;
    const int w   = tid >> 6;          // wave = 16-token slab
    const int l   = tid & 63;
    const int g   = blockIdx.x;

    // A staging map: 4 rounds x (16 rows x 16 float4-chunks) -- coalesced
    const int s_tok = tid >> 4;        // 0..15
    const int s_c   = tid & 15;        // k-chunk: floats s_c*4..s_c*4+3
    // W staging map: thread -> expert row, two 8-float chunks (wc*8, wc*8+32)
    const int we = tid >> 2;           // 0..63
    const int wc = tid & 3;

    const float* Abase = A + (size_t)g * 64 * HIDDEN;
    const float* WBase = W + (size_t)we * HIDDEN;

    f32x4 acc[4];
    #pragma unroll
    for (int n = 0; n < 4; ++n) acc[n] = (f32x4){0.f, 0.f, 0.f, 0.f};

    // A: two static prefetch sets (rule #20); W: one set
    float4 arA0, arA1, arA2, arA3;
    float4 arB0, arB1, arB2, arB3;
    float4 wr0, wr1, wr2, wr3;

    #define LOADA(S, win) do {                                               \
        const float* p_ = Abase + (size_t)(win) * BKW + s_c * 4;             \
        ar##S##0 = *(const float4*)(p_ + (size_t)(s_tok     ) * HIDDEN);     \
        ar##S##1 = *(const float4*)(p_ + (size_t)(s_tok + 16) * HIDDEN);     \
        ar##S##2 = *(const float4*)(p_ + (size_t)(s_tok + 32) * HIDDEN);     \
        ar##S##3 = *(const float4*)(p_ + (size_t)(s_tok + 48) * HIDDEN);     \
    } while (0)

    #define LOADW(win) do {                                                  \
        const float* q_ = WBase + (size_t)(win) * BKW + wc * 8;              \
        wr0 = *(const float4*)(q_);                                          \
        wr1 = *(const float4*)(q_ + 4);                                      \
        wr2 = *(const float4*)(q_ + 32);                                     \
        wr3 = *(const float4*)(q_ + 36);                                     \
    } while (0)

    // split one float4 into hi/lo half4 and store to (HS,LS) at half-offset OFF
    #define SPLIT4(HS, LS, v, OFF) do {                                      \
        _Float16 h0_ = (_Float16)(v).x, h1_ = (_Float16)(v).y;               \
        _Float16 h2_ = (_Float16)(v).z, h3_ = (_Float16)(v).w;               \
        half4 hh_ = {h0_, h1_, h2_, h3_};                                    \
        half4 ll_ = {(_Float16)((v).x - (float)h0_),                         \
                     (_Float16)((v).y - (float)h1_),                         \
                     (_Float16)((v).z - (float)h2_),                         \
                     (_Float16)((v).w - (float)h3_)};                        \
        *(half4*)(&(HS)[(OFF)]) = hh_;                                       \
        *(half4*)(&(LS)[(OFF)]) = ll_;                                       \
    } while (0)

    #define STAGE(S) do {                                                    \
        SPLIT4(Ahs, Als, ar##S##0, (s_tok     ) * LDH + s_c * 4);            \
        SPLIT4(Ahs, Als, ar##S##1, (s_tok + 16) * LDH + s_c * 4);            \
        SPLIT4(Ahs, Als, ar##S##2, (s_tok + 32) * LDH + s_c * 4);            \
        SPLIT4(Ahs, Als, ar##S##3, (s_tok + 48) * LDH + s_c * 4);            \
        SPLIT4(Whs, Wls, wr0, we * LDH + wc * 8);                            \
        SPLIT4(Whs, Wls, wr1, we * LDH + wc * 8 + 4);                        \
        SPLIT4(Whs, Wls, wr2, we * LDH + wc * 8 + 32);                       \
        SPLIT4(Whs, Wls, wr3, we * LDH + wc * 8 + 36);                       \
    } while (0)

    #define COMPUTE() do {                                                   \
        _Pragma("unroll")                                                    \
        for (int ks = 0; ks < 2; ++ks) {                                     \
            const int ko = ks * 32 + (l >> 4) * 8;                           \
            half8 ahi = *(const half8*)(&Ahs[(w * 16 + (l & 15)) * LDH + ko]); \
            half8 alo = *(const half8*)(&Als[(w * 16 + (l & 15)) * LDH + ko]); \
            _Pragma("unroll")                                                \
            for (int n = 0; n < 4; ++n) {                                    \
                half8 bh = *(const half8*)(&Whs[(n * 16 + (l & 15)) * LDH + ko]); \
                half8 bl = *(const half8*)(&Wls[(n * 16 + (l & 15)) * LDH + ko]); \
                acc[n] = __builtin_amdgcn_mfma_f32_16x16x32_f16(ahi, bh, acc[n], 0, 0, 0); \
                acc[n] = __builtin_amdgcn_mfma_f32_16x16x32_f16(ahi, bl, acc[n], 0, 0, 0); \
                acc[n] = __builtin_amdgcn_mfma_f32_16x16x32_f16(alo, bh, acc[n], 0, 0, 0); \
            }                                                                \
        }                                                                    \
    } while (0)

    // raw barrier: drain own LDS ops only (cross-wave visibility); global
    // prefetches stay in flight (counted vmcnt at their cvt-use).
    #define BARRAW() do {                                                    \
        asm volatile("s_waitcnt lgkmcnt(0)" ::: "memory");                   \
        __builtin_amdgcn_sched_barrier(0);                                   \
        __builtin_amdgcn_s_barrier();                                        \
        __builtin_amdgcn_sched_barrier(0);                                   \
    } while (0)

    // ---- prologue: A 2-deep, W 1-deep ----
    LOADA(A, 0);
    LOADW(0);
    LOADA(B, 1);

    #pragma unroll 1
    for (int s = 0; s < NWIN; s += 2) {
        BARRAW();                                // prev window's reads done
        STAGE(A);                                // window s (A-set A, W set)
        if (s + 1 < NWIN) LOADW(s + 1);          // W next window (L2, short)
        if (s + 2 < NWIN) LOADA(A, s + 2);       // A two windows ahead
        BARRAW();                                // window s published
        COMPUTE();                               // window s

        BARRAW();                                // reads done
        STAGE(B);                                // window s+1 (A-set B)
        if (s + 2 < NWIN) LOADW(s + 2);
        if (s + 3 < NWIN) LOADA(B, s + 3);
        BARRAW();                                // window s+1 published
        COMPUTE();                               // window s+1
    }
    #undef LOADA
    #undef LOADW
    #undef SPLIT4
    #undef STAGE
    #undef COMPUTE
    #undef BARRAW

    // ---- epilogue: logits (+bias) to LDS, top-8 + softmax + scatter ----
    __syncthreads();                           // staging LDS dead; alias as float
    float* lg = (float*)hsm;                   // [64 tok][68]
    float* sc = (float*)hsm + 64 * 68;         // [64 tok][65]

    // D layout (verified r8): token row = (l>>4)*4+q, expert col = n*16+(l&15)
    #pragma unroll
    for (int n = 0; n < 4; ++n) {
        float b = bias[n * 16 + (l & 15)];
        #pragma unroll
        for (int q = 0; q < 4; ++q) {
            int trow = w * 16 + (l >> 4) * 4 + q;
            lg[trow * 68 + n * 16 + (l & 15)] = acc[n][q] + b;
        }
    }
    for (int i = tid; i < 64 * 65; i += 256) sc[i] = 0.f;
    __syncthreads();

    if (tid < 64) {
        const int t = tid;
        float v[64];
        #pragma unroll
        for (int e = 0; e < 64; ++e) v[e] = lg[t * 68 + e];

        float tvals[TOPK]; int tix[TOPK]; float probs[TOPK];
        unsigned long long chosen = 0ull;
        #pragma unroll
        for (int j = 0; j < TOPK; ++j) {
            float best = -INFINITY; int bi = 0;
            #pragma unroll
            for (int e = 0; e < 64; ++e) {
                bool ok = ((chosen >> e) & 1ull) == 0ull;
                if (ok && v[e] > best) { best = v[e]; bi = e; }  // strict >: lowest idx on tie
            }
            chosen |= (1ull << bi);
            tvals[j] = best; tix[j] = bi;
        }
        float m = tvals[0];
        float ssum = 0.f;
        #pragma unroll
        for (int j = 0; j < TOPK; ++j) { probs[j] = __expf(tvals[j] - m); ssum += probs[j]; }
        float inv = 1.f / ssum;
        #pragma unroll
        for (int j = 0; j < TOPK; ++j) probs[j] *= inv;

        #pragma unroll
        for (int j = 0; j < TOPK; ++j) sc[t * 65 + tix[j]] = probs[j];

        float* oidx = out + (size_t)TOKENS * EXPERTS;
        const int token = g * 64 + t;
        #pragma unroll
        for (int j = 0; j < TOPK; ++j) oidx[(size_t)token * TOPK + j] = (float)tix[j];
    }
    __syncthreads();

    // ---- coalesced score write: 64 tokens x 64 experts = 1024 float4 ----
    float* oscore = out + (size_t)g * 4096;
    #pragma unroll
    for (int p = 0; p < 4; ++p) {
        int fi  = tid + 256 * p;               // float4 index 0..1023
        int tok = fi >> 4;
        int es  = (fi & 15) * 4;
        float4 vv;
        vv.x = sc[tok * 65 + es + 0];
        vv.y = sc[tok * 65 + es + 1];
        vv.z = sc[tok * 65 + es + 2];
        vv.w = sc[tok * 65 + es + 3];
        *(float4*)(oscore + (size_t)fi * 4) = vv;
    }
}

extern "C" void kernel_launch(void* const* d_in, const int* in_sizes, int n_in,
                              void* d_out, int out_size, void* d_ws, size_t ws_size,
                              hipStream_t stream) {
    const float* A    = (const float*)d_in[0];   // [32768, 2048] fp32
    const float* W    = (const float*)d_in[1];   // [64, 2048] fp32
    const float* bias = (const float*)d_in[2];   // [64] fp32
    float* out = (float*)d_out;                  // scores (32768*64) ++ idx (32768*8)
    (void)d_ws; (void)ws_size;

    router_p2<<<TOKENS / 64, 256, 0, stream>>>(A, W, bias, out);
}